// Round 16
// baseline (2866.512 us; speedup 1.0000x reference)
//
#include <hip/hip_runtime.h>

typedef unsigned short u16;
typedef _Float16 f16;
typedef __attribute__((ext_vector_type(8))) _Float16 f16x8;
typedef __attribute__((ext_vector_type(4))) float f32x4;

#define B_TOT 4096
#define T_STEPS 128
#define SMEM_BYTES 113024
#define LSCALE 2048.f
#define LINV   4.8828125e-4f   // 1/2048, exact

__device__ __forceinline__ u16 f2h(float x) {
  union { f16 h; u16 u; } v; v.h = (f16)x; return v.u;
}
__device__ __forceinline__ float h2f(u16 b) {
  union { u16 u; f16 h; } v; v.u = b; return (float)v.h;
}
// 2-limb fp16 split with scaled low limb: x ~= h + l/2048 to ~2^-22 rel.
__device__ __forceinline__ void split2(float x, u16& h, u16& l) {
  h = f2h(x);
  float r = x - h2f(h);
  l = f2h(r * LSCALE);
}
__device__ __forceinline__ float fastrcp(float x) {   // v_rcp_f32, ~1 ulp
  return __builtin_amdgcn_rcpf(x);
}
__device__ __forceinline__ float lsw(float u) {       // 0.909 * u * sigmoid(u)
  return 0.909f * u * fastrcp(1.f + __expf(-u));
}
__device__ __forceinline__ float tanh_fast(float u) {
  return 1.f - 2.f * fastrcp(1.f + __expf(2.f * u));
}
__device__ __forceinline__ f32x4 mmh(f16x8 a, f16x8 b, f32x4 c) {
  return __builtin_amdgcn_mfma_f32_16x16x32_f16(a, b, c, 0, 0, 0);
}
__device__ __forceinline__ f16x8 ldfrag(const u16* p) { return *(const f16x8*)p; }

// Pre-fragment W[K][O] (row-major, ld ldW) into 2 fp16 limbs in MFMA fragment order:
// dst[((nt*KS+ks)*64+lane)*8+e] = W[rowOff + ks*32 + (lane>>4)*8 + e][nt*16 + (lane&15)]
__global__ void frag_w2(const float* __restrict__ W, int KS, int ldW, int rowOff,
                        u16* __restrict__ dh, u16* __restrict__ dl, int nElems) {
  int i = blockIdx.x * blockDim.x + threadIdx.x;
  if (i >= nElems) return;
  int e = i & 7, lane = (i >> 3) & 63, rest = i >> 9;
  int ks = rest % KS, nt = rest / KS;
  int row = rowOff + ks * 32 + ((lane >> 4) * 8) + e;
  int col = nt * 16 + (lane & 15);
  float w = W[row * ldW + col];
  u16 h, l; split2(w, h, l);
  dh[i] = h; dl[i] = l;
}

__global__ __launch_bounds__(512, 1) void sde_gen(
    const float* __restrict__ ts, const float* __restrict__ init_noise,
    const float* __restrict__ dW,
    const float* __restrict__ ib0, const float* __restrict__ ib1, const float* __restrict__ ib2,
    const float* __restrict__ gw0, const float* __restrict__ gb0,
    const float* __restrict__ gb1, const float* __restrict__ gb2,
    const float* __restrict__ rw, const float* __restrict__ rb,
    const u16* __restrict__ fiw0h, const u16* __restrict__ fiw0l,
    const u16* __restrict__ fiw1h, const u16* __restrict__ fiw1l,
    const u16* __restrict__ fiw2h, const u16* __restrict__ fiw2l,
    const u16* __restrict__ fgw0h, const u16* __restrict__ fgw0l,
    const u16* __restrict__ fgw1h, const u16* __restrict__ fgw1l,
    const u16* __restrict__ fgw2h, const u16* __restrict__ fgw2l,
    float* __restrict__ out) {
  extern __shared__ char smem[];
  u16*   s_w1h  = (u16*)(smem);            // [16384] gw1 hi frags
  u16*   s_w1l  = (u16*)(smem + 32768);    // [16384] gw1 lo frags
  u16*   s_ax   = (u16*)(smem + 65536);    // [2][16][72]
  u16*   s_ah0  = (u16*)(smem + 70144);    // [2][16][136]
  u16*   s_ah1  = (u16*)(smem + 78848);    // [2][16][136]
  float* s_z    = (float*)(smem + 87552);  // [16][64]
  float* s_zh   = (float*)(smem + 91648);  // [16][64]
  float* s_v    = (float*)(smem + 95744);  // [16][68]
  float* s_w    = (float*)(smem + 100096); // [16][68]
  float* s_dw   = (float*)(smem + 104448); // [2][16][17]
  float* s_ts   = (float*)(smem + 106624); // [128]
  float* s_gb0  = (float*)(smem + 107136);
  float* s_w0r0 = (float*)(smem + 107648);
  float* s_gb1  = (float*)(smem + 108160);
  float* s_gb2  = (float*)(smem + 108672); // [1024]
  float* s_rw   = (float*)(smem + 112768); // [64]
#define AX(L,r,c)   s_ax [((L)*16+(r))*72 +(c)]
#define AH0(L,r,c)  s_ah0[((L)*16+(r))*136+(c)]
#define AH1(L,r,c)  s_ah1[((L)*16+(r))*136+(c)]
#define ZV(r,c)  s_z [(r)*64+(c)]
#define ZH(r,c)  s_zh[(r)*64+(c)]
#define SV(r,c)  s_v [(r)*68+(c)]
#define SW(r,c)  s_w [(r)*68+(c)]
#define SDW(b,r,c) s_dw[((b)*16+(r))*17+(c)]

  const int tid = threadIdx.x;
  const int wv = tid >> 6;        // 0..7
  const int lane = tid & 63;
  const int l15 = lane & 15, lg = lane >> 4;
  const int R = blockIdx.x * 16;
  const int jrot = blockIdx.x & 7;   // de-correlate W2 L2-line access across blocks

  // ---- one-time loads ----
  for (int i = tid; i < 128; i += 512) {
    s_ts[i] = ts[i]; s_gb0[i] = gb0[i]; s_gb1[i] = gb1[i]; s_w0r0[i] = gw0[i];
  }
  for (int i = tid; i < 1024; i += 512) s_gb2[i] = gb2[i];
  if (tid < 64) s_rw[tid] = rw[tid];
  for (int i = tid; i < 2048; i += 512) {   // gw1 limb frags -> LDS (64 KB)
    ((f16x8*)s_w1h)[i] = ((const f16x8*)fgw1h)[i];
    ((f16x8*)s_w1l)[i] = ((const f16x8*)fgw1l)[i];
  }
  for (int i = tid; i < 16 * 64; i += 512) {
    int r = i >> 6, k = i & 63;
    float x = init_noise[(R + r) * 64 + k];
    u16 h, l; split2(x, h, l);
    AX(0,r,k) = h; AX(1,r,k) = l;
  }
  if (tid < 256) { // dWs[0]; zero dWs buf 1
    float sdt = sqrtf(ts[1] - ts[0]);
    int r = tid >> 4, nn = tid & 15;
    SDW(0, r, nn) = dW[(0 * B_TOT + R + r) * 16 + nn] * sdt;
    SDW(1, r, nn) = 0.f;
  }
  __syncthreads();

  // ---------------- initial MLP (fp16x3-product) ----------------
  { // L1, K=64, tile t = wv (8 tiles)
    f32x4 aA = {0,0,0,0}, aB = {0,0,0,0};
#pragma unroll
    for (int ks = 0; ks < 2; ++ks) {
      f16x8 xh = *(const f16x8*)&AX(0, l15, ks*32 + lg*8);
      f16x8 xl = *(const f16x8*)&AX(1, l15, ks*32 + lg*8);
      int off = ((wv * 2 + ks) * 64 + lane) * 8;
      f16x8 bh = ldfrag(fiw0h + off), bl = ldfrag(fiw0l + off);
      aA = mmh(xh, bh, aA);
      aB = mmh(xh, bl, mmh(xl, bh, aB));
    }
#pragma unroll
    for (int reg = 0; reg < 4; ++reg) {
      int r = lg * 4 + reg, c = wv * 16 + l15;
      float act = lsw((aA[reg] + aB[reg] * LINV) + ib0[c]);
      u16 h, l; split2(act, h, l);
      AH0(0,r,c) = h; AH0(1,r,c) = l;
    }
  }
  __syncthreads();
  { // L2, K=128, tile t = wv
    f32x4 aA = {0,0,0,0}, aB = {0,0,0,0};
#pragma unroll
    for (int ks = 0; ks < 4; ++ks) {
      f16x8 xh = *(const f16x8*)&AH0(0, l15, ks*32 + lg*8);
      f16x8 xl = *(const f16x8*)&AH0(1, l15, ks*32 + lg*8);
      int off = ((wv * 4 + ks) * 64 + lane) * 8;
      f16x8 bh = ldfrag(fiw1h + off), bl = ldfrag(fiw1l + off);
      aA = mmh(xh, bh, aA);
      aB = mmh(xh, bl, mmh(xl, bh, aB));
    }
#pragma unroll
    for (int reg = 0; reg < 4; ++reg) {
      int r = lg * 4 + reg, c = wv * 16 + l15;
      float act = lsw((aA[reg] + aB[reg] * LINV) + ib1[c]);
      u16 h, l; split2(act, h, l);
      AH1(0,r,c) = h; AH1(1,r,c) = l;
    }
  }
  __syncthreads();
  if (wv < 4) { // L3 init: O=64, tile wv
    f32x4 aA = {0,0,0,0}, aB = {0,0,0,0};
#pragma unroll
    for (int ks = 0; ks < 4; ++ks) {
      f16x8 xh = *(const f16x8*)&AH1(0, l15, ks*32 + lg*8);
      f16x8 xl = *(const f16x8*)&AH1(1, l15, ks*32 + lg*8);
      int off = ((wv * 4 + ks) * 64 + lane) * 8;
      f16x8 bh = ldfrag(fiw2h + off), bl = ldfrag(fiw2l + off);
      aA = mmh(xh, bh, aA);
      aB = mmh(xh, bl, mmh(xl, bh, aB));
    }
#pragma unroll
    for (int reg = 0; reg < 4; ++reg) {
      int r = lg * 4 + reg, c = wv * 16 + l15;
      float x0 = (aA[reg] + aB[reg] * LINV) + ib2[c];
      ZV(r,c) = x0; ZH(r,c) = x0;
      u16 h, l; split2(x0, h, l);
      AX(0,r,c) = h; AX(1,r,c) = l;
    }
  }
  __syncthreads();

  const float rbv = rb[0];

  // ---- resident W2-hi fragments, pinned to AGPRs (128 regs): slot j <-> tile
  // wv*8 + ((j+jrot)&7). fp16 transients leave ~115 VGPR < 128 arch budget.
  f16x8 w2fh[8][4];
#pragma unroll
  for (int j = 0; j < 8; ++j)
#pragma unroll
    for (int ks = 0; ks < 4; ++ks)
      w2fh[j][ks] =
          ldfrag(fgw2h + (((wv * 8 + ((j + jrot) & 7)) * 4 + ks) * 64 + lane) * 8);
#pragma unroll
  for (int j = 0; j < 8; ++j)
#pragma unroll
    for (int ks = 0; ks < 4; ++ks)
      asm volatile("" : "+a"(w2fh[j][ks]));   // AGPR class: spill-proof residency

// W2 tile compute: A-hi from AGPR slot J, streamed low-limb buffer WL, tile TI
#define L3_COMPUTE_A(J, WL, TI)                                                 \
  {                                                                             \
    f32x4 aA = {0,0,0,0}, aB = {0,0,0,0};                                       \
    _Pragma("unroll")                                                           \
    for (int ks = 0; ks < 4; ++ks) {                                            \
      aA = mmh(w2fh[J][ks], bfh[ks], aA);                                       \
      aB = mmh(w2fh[J][ks], bfl[ks], mmh(WL[ks], bfh[ks], aB));                 \
    }                                                                           \
    float pw = 0.f, pv = 0.f;                                                   \
    _Pragma("unroll")                                                           \
    for (int reg = 0; reg < 4; ++reg) {                                         \
      int c = (TI) * 16 + lg * 4 + reg;                                         \
      float g = tanh_fast((aA[reg] + aB[reg] * LINV) + s_gb2[c]);               \
      pw += g * dw0v[reg];                                                      \
      pv += g * dw1v[reg];                                                      \
    }                                                                           \
    pw += __shfl_xor(pw, 16); pw += __shfl_xor(pw, 32);                         \
    pv += __shfl_xor(pv, 16); pv += __shfl_xor(pv, 32);                         \
    if (lane < 16) { SW(lane, (TI)) = pw; SV(lane, (TI)) = pv; }                \
  }

#define L3_PREFETCH_L(WL, TI)                                                   \
  {                                                                             \
    _Pragma("unroll")                                                           \
    for (int ks = 0; ks < 4; ++ks) {                                            \
      WL[ks] = ldfrag(fgw2l + (((TI) * 4 + ks) * 64 + lane) * 8);               \
    }                                                                           \
  }

  // ---------------- time loop ----------------
  for (int n = 0; n < T_STEPS; ++n) {
    if (n > 0) {
      // phase A: zhat_n = 2z - zhat + v ; z += 0.5 v ; stage x limbs
#pragma unroll
      for (int i = 0; i < 2; ++i) {
        int r = wv * 2 + i, h = lane;
        float z = ZV(r,h), zh = ZH(r,h), v = SV(r,h);
        float zhn = 2.f * z - zh + v;
        ZH(r,h) = zhn;
        u16 hh, ll; split2(zhn, hh, ll);
        AX(0,r,h) = hh; AX(1,r,h) = ll;
        ZV(r,h) = z + 0.5f * v;
      }
      if (n < T_STEPS - 1 && tid < 256) {
        float sdt = sqrtf(s_ts[n + 1] - s_ts[n]);
        int r = tid >> 4, nn = tid & 15;
        SDW(n & 1, r, nn) = dW[(n * B_TOT + R + r) * 16 + nn] * sdt;
      }
      __syncthreads();
    }
    const float tval = s_ts[n];
    { // L1: h0 = lsw(x@gw0[1:] + gb0 + t*gw0[0]), tile t = wv, gw0 streamed (L2-hit)
      f32x4 aA = {0,0,0,0}, aB = {0,0,0,0};
#pragma unroll
      for (int ks = 0; ks < 2; ++ks) {
        f16x8 xh = *(const f16x8*)&AX(0, l15, ks*32 + lg*8);
        f16x8 xl = *(const f16x8*)&AX(1, l15, ks*32 + lg*8);
        int off = ((wv * 2 + ks) * 64 + lane) * 8;
        f16x8 bh = ldfrag(fgw0h + off);
        f16x8 bl = ldfrag(fgw0l + off);
        aA = mmh(xh, bh, aA);
        aB = mmh(xh, bl, mmh(xl, bh, aB));
      }
#pragma unroll
      for (int reg = 0; reg < 4; ++reg) {
        int r = lg * 4 + reg, c = wv * 16 + l15;
        float act = lsw((aA[reg] + aB[reg] * LINV) + s_gb0[c] + tval * s_w0r0[c]);
        u16 h, l; split2(act, h, l);
        AH0(0,r,c) = h; AH0(1,r,c) = l;
      }
    }
    __syncthreads();
    f16x8 wlA[4], wlB[4];   // W2-lo stream double buffer (32 regs)
    const int t0 = wv * 8 + jrot;
    const int t1 = wv * 8 + ((1 + jrot) & 7);
    const int t2 = wv * 8 + ((2 + jrot) & 7);
    const int t3 = wv * 8 + ((3 + jrot) & 7);
    const int t4 = wv * 8 + ((4 + jrot) & 7);
    const int t5 = wv * 8 + ((5 + jrot) & 7);
    const int t6 = wv * 8 + ((6 + jrot) & 7);
    const int t7 = wv * 8 + ((7 + jrot) & 7);
    { // L2: h1 = lsw(h0@gw1 + gb1), tile t = wv, gw1 limbs from LDS
      // issue j=0 W2-lo prefetch first: latency hides under L2 MFMAs
      L3_PREFETCH_L(wlA, t0);
      f32x4 aA = {0,0,0,0}, aB = {0,0,0,0};
#pragma unroll
      for (int ks = 0; ks < 4; ++ks) {
        f16x8 xh = *(const f16x8*)&AH0(0, l15, ks*32 + lg*8);
        f16x8 xl = *(const f16x8*)&AH0(1, l15, ks*32 + lg*8);
        int off = ((wv * 4 + ks) * 64 + lane) * 8;
        f16x8 bh = *(const f16x8*)&s_w1h[off];
        f16x8 bl = *(const f16x8*)&s_w1l[off];
        aA = mmh(xh, bh, aA);
        aB = mmh(xh, bl, mmh(xl, bh, aB));
      }
#pragma unroll
      for (int reg = 0; reg < 4; ++reg) {
        int r = lg * 4 + reg, c = wv * 16 + l15;
        float act = lsw((aA[reg] + aB[reg] * LINV) + s_gb1[c]);
        u16 h, l; split2(act, h, l);
        AH1(0,r,c) = h; AH1(1,r,c) = l;
      }
    }
    __syncthreads();
    // L3 transposed (D' = W2^T h1^T): W2-hi AGPR-resident, W2-lo pipelined
    float dw0v[4], dw1v[4];
#pragma unroll
    for (int reg = 0; reg < 4; ++reg) {
      dw0v[reg] = SDW((n - 1) & 1, l15, lg * 4 + reg);
      dw1v[reg] = SDW(n & 1,       l15, lg * 4 + reg);
    }
    f16x8 bfh[4], bfl[4];
#pragma unroll
    for (int ks = 0; ks < 4; ++ks) {
      bfh[ks] = *(const f16x8*)&AH1(0, l15, ks*32 + lg*8);
      bfl[ks] = *(const f16x8*)&AH1(1, l15, ks*32 + lg*8);
    }
    L3_PREFETCH_L(wlB, t1);  L3_COMPUTE_A(0, wlA, t0);
    __builtin_amdgcn_sched_barrier(0);
    L3_PREFETCH_L(wlA, t2);  L3_COMPUTE_A(1, wlB, t1);
    __builtin_amdgcn_sched_barrier(0);
    L3_PREFETCH_L(wlB, t3);  L3_COMPUTE_A(2, wlA, t2);
    __builtin_amdgcn_sched_barrier(0);
    L3_PREFETCH_L(wlA, t4);  L3_COMPUTE_A(3, wlB, t3);
    __builtin_amdgcn_sched_barrier(0);
    L3_PREFETCH_L(wlB, t5);  L3_COMPUTE_A(4, wlA, t4);
    __builtin_amdgcn_sched_barrier(0);
    L3_PREFETCH_L(wlA, t6);  L3_COMPUTE_A(5, wlB, t5);
    __builtin_amdgcn_sched_barrier(0);
    L3_PREFETCH_L(wlB, t7);  L3_COMPUTE_A(6, wlA, t6);
    __builtin_amdgcn_sched_barrier(0);
    L3_COMPUTE_A(7, wlB, t7);
    __syncthreads();
    // phase D: z_n = z + 0.5 w ; emit (ts, z.rw + rb)
#pragma unroll
    for (int i = 0; i < 2; ++i) {
      int r = wv * 2 + i, h = lane;
      float z = ZV(r,h);
      if (n > 0) { z += 0.5f * SW(r,h); ZV(r,h) = z; }
      float p = z * s_rw[h];
#pragma unroll
      for (int off = 32; off >= 1; off >>= 1) p += __shfl_xor(p, off);
      if (lane == 0) {
        int o = ((R + r) * T_STEPS + n) * 2;
        out[o] = tval; out[o + 1] = p + rbv;
      }
    }
  }
}

extern "C" void kernel_launch(void* const* d_in, const int* in_sizes, int n_in,
                              void* d_out, int out_size, void* d_ws, size_t ws_size,
                              hipStream_t stream) {
  (void)in_sizes; (void)n_in; (void)out_size; (void)ws_size;
  const float* ts = (const float*)d_in[0];
  const float* init_noise = (const float*)d_in[2];
  const float* dW  = (const float*)d_in[3];
  const float* iw0 = (const float*)d_in[4];
  const float* ib0 = (const float*)d_in[5];
  const float* iw1 = (const float*)d_in[6];
  const float* ib1 = (const float*)d_in[7];
  const float* iw2 = (const float*)d_in[8];
  const float* ib2 = (const float*)d_in[9];
  const float* gw0 = (const float*)d_in[10];
  const float* gb0 = (const float*)d_in[11];
  const float* gw1 = (const float*)d_in[12];
  const float* gb1 = (const float*)d_in[13];
  const float* gw2 = (const float*)d_in[14];
  const float* gb2 = (const float*)d_in[15];
  const float* rw  = (const float*)d_in[16];
  const float* rb  = (const float*)d_in[17];

  u16* ws = (u16*)d_ws;
  const int LO = 188416;  // elems per limb block
  u16* fiw0h = ws + 0;      u16* fiw0l = ws + LO + 0;
  u16* fiw1h = ws + 8192;   u16* fiw1l = ws + LO + 8192;
  u16* fiw2h = ws + 24576;  u16* fiw2l = ws + LO + 24576;
  u16* fgw0h = ws + 32768;  u16* fgw0l = ws + LO + 32768;
  u16* fgw1h = ws + 40960;  u16* fgw1l = ws + LO + 40960;
  u16* fgw2h = ws + 57344;  u16* fgw2l = ws + LO + 57344;

  frag_w2<<<32,  256, 0, stream>>>(iw0, 2, 128, 0, fiw0h, fiw0l, 8192);
  frag_w2<<<64,  256, 0, stream>>>(iw1, 4, 128, 0, fiw1h, fiw1l, 16384);
  frag_w2<<<32,  256, 0, stream>>>(iw2, 4, 64,  0, fiw2h, fiw2l, 8192);
  frag_w2<<<32,  256, 0, stream>>>(gw0, 2, 128, 1, fgw0h, fgw0l, 8192);
  frag_w2<<<64,  256, 0, stream>>>(gw1, 4, 128, 0, fgw1h, fgw1l, 16384);
  frag_w2<<<512, 256, 0, stream>>>(gw2, 4, 1024, 0, fgw2h, fgw2l, 131072);

  hipFuncSetAttribute((const void*)sde_gen,
                      hipFuncAttributeMaxDynamicSharedMemorySize, SMEM_BYTES);
  sde_gen<<<256, 512, SMEM_BYTES, stream>>>(
      ts, init_noise, dW, ib0, ib1, ib2, gw0, gb0, gb1, gb2, rw, rb,
      fiw0h, fiw0l, fiw1h, fiw1l, fiw2h, fiw2l,
      fgw0h, fgw0l, fgw1h, fgw1l, fgw2h, fgw2l,
      (float*)d_out);
}

// Round 17
// 812.418 us; speedup vs baseline: 3.5284x; 3.5284x over previous
//
#include <hip/hip_runtime.h>

typedef unsigned short u16;
typedef _Float16 f16;
typedef __attribute__((ext_vector_type(8))) _Float16 f16x8;
typedef __attribute__((ext_vector_type(4))) float f32x4;

#define B_TOT 4096
#define T_STEPS 128
#define SMEM_BYTES 113024
#define LSCALE 2048.f
#define LINV   4.8828125e-4f   // 1/2048, exact

__device__ __forceinline__ u16 f2h(float x) {
  union { f16 h; u16 u; } v; v.h = (f16)x; return v.u;
}
__device__ __forceinline__ float h2f(u16 b) {
  union { u16 u; f16 h; } v; v.u = b; return (float)v.h;
}
// 2-limb fp16 split with scaled low limb: x ~= h + l/2048 to ~2^-22 rel.
__device__ __forceinline__ void split2(float x, u16& h, u16& l) {
  h = f2h(x);
  float r = x - h2f(h);
  l = f2h(r * LSCALE);
}
__device__ __forceinline__ float fastrcp(float x) {   // v_rcp_f32, ~1 ulp
  return __builtin_amdgcn_rcpf(x);
}
__device__ __forceinline__ float lsw(float u) {       // 0.909 * u * sigmoid(u)
  return 0.909f * u * fastrcp(1.f + __expf(-u));
}
__device__ __forceinline__ float tanh_fast(float u) {
  return 1.f - 2.f * fastrcp(1.f + __expf(2.f * u));
}
__device__ __forceinline__ f32x4 mmh(f16x8 a, f16x8 b, f32x4 c) {
  return __builtin_amdgcn_mfma_f32_16x16x32_f16(a, b, c, 0, 0, 0);
}
__device__ __forceinline__ f16x8 ldfrag(const u16* p) { return *(const f16x8*)p; }

// Pre-fragment W[K][O] (row-major, ld ldW) into 2 fp16 limbs in MFMA fragment order:
// dst[((nt*KS+ks)*64+lane)*8+e] = W[rowOff + ks*32 + (lane>>4)*8 + e][nt*16 + (lane&15)]
__global__ void frag_w2(const float* __restrict__ W, int KS, int ldW, int rowOff,
                        u16* __restrict__ dh, u16* __restrict__ dl, int nElems) {
  int i = blockIdx.x * blockDim.x + threadIdx.x;
  if (i >= nElems) return;
  int e = i & 7, lane = (i >> 3) & 63, rest = i >> 9;
  int ks = rest % KS, nt = rest / KS;
  int row = rowOff + ks * 32 + ((lane >> 4) * 8) + e;
  int col = nt * 16 + (lane & 15);
  float w = W[row * ldW + col];
  u16 h, l; split2(w, h, l);
  dh[i] = h; dl[i] = l;
}

__global__ __attribute__((amdgpu_flat_work_group_size(512, 512),
                          amdgpu_waves_per_eu(2, 2)))
void sde_gen(
    const float* __restrict__ ts, const float* __restrict__ init_noise,
    const float* __restrict__ dW,
    const float* __restrict__ ib0, const float* __restrict__ ib1, const float* __restrict__ ib2,
    const float* __restrict__ gw0, const float* __restrict__ gb0,
    const float* __restrict__ gb1, const float* __restrict__ gb2,
    const float* __restrict__ rw, const float* __restrict__ rb,
    const u16* __restrict__ fiw0h, const u16* __restrict__ fiw0l,
    const u16* __restrict__ fiw1h, const u16* __restrict__ fiw1l,
    const u16* __restrict__ fiw2h, const u16* __restrict__ fiw2l,
    const u16* __restrict__ fgw0h, const u16* __restrict__ fgw0l,
    const u16* __restrict__ fgw1h, const u16* __restrict__ fgw1l,
    const u16* __restrict__ fgw2h, const u16* __restrict__ fgw2l,
    float* __restrict__ out) {
  extern __shared__ char smem[];
  u16*   s_w1h  = (u16*)(smem);            // [16384] gw1 hi frags
  u16*   s_w1l  = (u16*)(smem + 32768);    // [16384] gw1 lo frags
  u16*   s_ax   = (u16*)(smem + 65536);    // [2][16][72]
  u16*   s_ah0  = (u16*)(smem + 70144);    // [2][16][136]
  u16*   s_ah1  = (u16*)(smem + 78848);    // [2][16][136]
  float* s_z    = (float*)(smem + 87552);  // [16][64]
  float* s_zh   = (float*)(smem + 91648);  // [16][64]
  float* s_v    = (float*)(smem + 95744);  // [16][68]
  float* s_w    = (float*)(smem + 100096); // [16][68]
  float* s_dw   = (float*)(smem + 104448); // [2][16][17]
  float* s_ts   = (float*)(smem + 106624); // [128]
  float* s_gb0  = (float*)(smem + 107136);
  float* s_w0r0 = (float*)(smem + 107648);
  float* s_gb1  = (float*)(smem + 108160);
  float* s_gb2  = (float*)(smem + 108672); // [1024]
  float* s_rw   = (float*)(smem + 112768); // [64]
#define AX(L,r,c)   s_ax [((L)*16+(r))*72 +(c)]
#define AH0(L,r,c)  s_ah0[((L)*16+(r))*136+(c)]
#define AH1(L,r,c)  s_ah1[((L)*16+(r))*136+(c)]
#define ZV(r,c)  s_z [(r)*64+(c)]
#define ZH(r,c)  s_zh[(r)*64+(c)]
#define SV(r,c)  s_v [(r)*68+(c)]
#define SW(r,c)  s_w [(r)*68+(c)]
#define SDW(b,r,c) s_dw[((b)*16+(r))*17+(c)]

  const int tid = threadIdx.x;
  const int wv = tid >> 6;        // 0..7
  const int lane = tid & 63;
  const int l15 = lane & 15, lg = lane >> 4;
  const int R = blockIdx.x * 16;
  const int jrot = blockIdx.x & 7;   // de-correlate W2 L2-line access across blocks

  // ---- one-time loads ----
  for (int i = tid; i < 128; i += 512) {
    s_ts[i] = ts[i]; s_gb0[i] = gb0[i]; s_gb1[i] = gb1[i]; s_w0r0[i] = gw0[i];
  }
  for (int i = tid; i < 1024; i += 512) s_gb2[i] = gb2[i];
  if (tid < 64) s_rw[tid] = rw[tid];
  for (int i = tid; i < 2048; i += 512) {   // gw1 limb frags -> LDS (64 KB)
    ((f16x8*)s_w1h)[i] = ((const f16x8*)fgw1h)[i];
    ((f16x8*)s_w1l)[i] = ((const f16x8*)fgw1l)[i];
  }
  for (int i = tid; i < 16 * 64; i += 512) {
    int r = i >> 6, k = i & 63;
    float x = init_noise[(R + r) * 64 + k];
    u16 h, l; split2(x, h, l);
    AX(0,r,k) = h; AX(1,r,k) = l;
  }
  if (tid < 256) { // dWs[0]; zero dWs buf 1
    float sdt = sqrtf(ts[1] - ts[0]);
    int r = tid >> 4, nn = tid & 15;
    SDW(0, r, nn) = dW[(0 * B_TOT + R + r) * 16 + nn] * sdt;
    SDW(1, r, nn) = 0.f;
  }
  __syncthreads();

  // ---------------- initial MLP (fp16x3-product) ----------------
  { // L1, K=64, tile t = wv (8 tiles)
    f32x4 aA = {0,0,0,0}, aB = {0,0,0,0};
#pragma unroll
    for (int ks = 0; ks < 2; ++ks) {
      f16x8 xh = *(const f16x8*)&AX(0, l15, ks*32 + lg*8);
      f16x8 xl = *(const f16x8*)&AX(1, l15, ks*32 + lg*8);
      int off = ((wv * 2 + ks) * 64 + lane) * 8;
      f16x8 bh = ldfrag(fiw0h + off), bl = ldfrag(fiw0l + off);
      aA = mmh(xh, bh, aA);
      aB = mmh(xh, bl, mmh(xl, bh, aB));
    }
#pragma unroll
    for (int reg = 0; reg < 4; ++reg) {
      int r = lg * 4 + reg, c = wv * 16 + l15;
      float act = lsw((aA[reg] + aB[reg] * LINV) + ib0[c]);
      u16 h, l; split2(act, h, l);
      AH0(0,r,c) = h; AH0(1,r,c) = l;
    }
  }
  __syncthreads();
  { // L2, K=128, tile t = wv
    f32x4 aA = {0,0,0,0}, aB = {0,0,0,0};
#pragma unroll
    for (int ks = 0; ks < 4; ++ks) {
      f16x8 xh = *(const f16x8*)&AH0(0, l15, ks*32 + lg*8);
      f16x8 xl = *(const f16x8*)&AH0(1, l15, ks*32 + lg*8);
      int off = ((wv * 4 + ks) * 64 + lane) * 8;
      f16x8 bh = ldfrag(fiw1h + off), bl = ldfrag(fiw1l + off);
      aA = mmh(xh, bh, aA);
      aB = mmh(xh, bl, mmh(xl, bh, aB));
    }
#pragma unroll
    for (int reg = 0; reg < 4; ++reg) {
      int r = lg * 4 + reg, c = wv * 16 + l15;
      float act = lsw((aA[reg] + aB[reg] * LINV) + ib1[c]);
      u16 h, l; split2(act, h, l);
      AH1(0,r,c) = h; AH1(1,r,c) = l;
    }
  }
  __syncthreads();
  if (wv < 4) { // L3 init: O=64, tile wv
    f32x4 aA = {0,0,0,0}, aB = {0,0,0,0};
#pragma unroll
    for (int ks = 0; ks < 4; ++ks) {
      f16x8 xh = *(const f16x8*)&AH1(0, l15, ks*32 + lg*8);
      f16x8 xl = *(const f16x8*)&AH1(1, l15, ks*32 + lg*8);
      int off = ((wv * 4 + ks) * 64 + lane) * 8;
      f16x8 bh = ldfrag(fiw2h + off), bl = ldfrag(fiw2l + off);
      aA = mmh(xh, bh, aA);
      aB = mmh(xh, bl, mmh(xl, bh, aB));
    }
#pragma unroll
    for (int reg = 0; reg < 4; ++reg) {
      int r = lg * 4 + reg, c = wv * 16 + l15;
      float x0 = (aA[reg] + aB[reg] * LINV) + ib2[c];
      ZV(r,c) = x0; ZH(r,c) = x0;
      u16 h, l; split2(x0, h, l);
      AX(0,r,c) = h; AX(1,r,c) = l;
    }
  }
  __syncthreads();

  const float rbv = rb[0];

// W2 tile compute: consumes buffer (WH,WL) for tile NT
#define L3_COMPUTE(WH, WL, NT)                                                  \
  {                                                                             \
    f32x4 aA = {0,0,0,0}, aB = {0,0,0,0};                                       \
    _Pragma("unroll")                                                           \
    for (int ks = 0; ks < 4; ++ks) {                                            \
      aA = mmh(WH[ks], bfh[ks], aA);                                            \
      aB = mmh(WH[ks], bfl[ks], mmh(WL[ks], bfh[ks], aB));                      \
    }                                                                           \
    float pw = 0.f, pv = 0.f;                                                   \
    _Pragma("unroll")                                                           \
    for (int reg = 0; reg < 4; ++reg) {                                         \
      int c = (NT) * 16 + lg * 4 + reg;                                         \
      float g = tanh_fast((aA[reg] + aB[reg] * LINV) + s_gb2[c]);               \
      pw += g * dw0v[reg];                                                      \
      pv += g * dw1v[reg];                                                      \
    }                                                                           \
    pw += __shfl_xor(pw, 16); pw += __shfl_xor(pw, 32);                         \
    pv += __shfl_xor(pv, 16); pv += __shfl_xor(pv, 32);                         \
    if (lane < 16) { SW(lane, (NT)) = pw; SV(lane, (NT)) = pv; }                \
  }

#define L3_PREFETCH(WH, WL, NT)                                                 \
  {                                                                             \
    _Pragma("unroll")                                                           \
    for (int ks = 0; ks < 4; ++ks) {                                            \
      int off = (((NT) * 4 + ks) * 64 + lane) * 8;                              \
      WH[ks] = ldfrag(fgw2h + off);                                             \
      WL[ks] = ldfrag(fgw2l + off);                                             \
    }                                                                           \
  }

  // ---------------- time loop ----------------
  for (int n = 0; n < T_STEPS; ++n) {
    if (n > 0) {
      // phase A: zhat_n = 2z - zhat + v ; z += 0.5 v ; stage x limbs
#pragma unroll
      for (int i = 0; i < 2; ++i) {
        int r = wv * 2 + i, h = lane;
        float z = ZV(r,h), zh = ZH(r,h), v = SV(r,h);
        float zhn = 2.f * z - zh + v;
        ZH(r,h) = zhn;
        u16 hh, ll; split2(zhn, hh, ll);
        AX(0,r,h) = hh; AX(1,r,h) = ll;
        ZV(r,h) = z + 0.5f * v;
      }
      if (n < T_STEPS - 1 && tid < 256) {
        float sdt = sqrtf(s_ts[n + 1] - s_ts[n]);
        int r = tid >> 4, nn = tid & 15;
        SDW(n & 1, r, nn) = dW[(n * B_TOT + R + r) * 16 + nn] * sdt;
      }
      __syncthreads();
    }
    const float tval = s_ts[n];
    { // L1: h0 = lsw(x@gw0[1:] + gb0 + t*gw0[0]), tile t = wv, gw0 streamed (L2-hit)
      f32x4 aA = {0,0,0,0}, aB = {0,0,0,0};
#pragma unroll
      for (int ks = 0; ks < 2; ++ks) {
        f16x8 xh = *(const f16x8*)&AX(0, l15, ks*32 + lg*8);
        f16x8 xl = *(const f16x8*)&AX(1, l15, ks*32 + lg*8);
        int off = ((wv * 2 + ks) * 64 + lane) * 8;
        f16x8 bh = ldfrag(fgw0h + off);
        f16x8 bl = ldfrag(fgw0l + off);
        aA = mmh(xh, bh, aA);
        aB = mmh(xh, bl, mmh(xl, bh, aB));
      }
#pragma unroll
      for (int reg = 0; reg < 4; ++reg) {
        int r = lg * 4 + reg, c = wv * 16 + l15;
        float act = lsw((aA[reg] + aB[reg] * LINV) + s_gb0[c] + tval * s_w0r0[c]);
        u16 h, l; split2(act, h, l);
        AH0(0,r,c) = h; AH0(1,r,c) = l;
      }
    }
    __syncthreads();
    f16x8 whA[4], wlA[4], whB[4], wlB[4];   // j-loop double buffer
    { // L2: h1 = lsw(h0@gw1 + gb1), tile t = wv, gw1 limbs from LDS
      // issue BOTH initial W2 prefetches: latency hides under L2 MFMAs.
      // waves_per_eu(2,2) grants 256-VGPR budget so this no longer spills.
      L3_PREFETCH(whA, wlA, wv * 8 + jrot);
      L3_PREFETCH(whB, wlB, wv * 8 + ((1 + jrot) & 7));
      f32x4 aA = {0,0,0,0}, aB = {0,0,0,0};
#pragma unroll
      for (int ks = 0; ks < 4; ++ks) {
        f16x8 xh = *(const f16x8*)&AH0(0, l15, ks*32 + lg*8);
        f16x8 xl = *(const f16x8*)&AH0(1, l15, ks*32 + lg*8);
        int off = ((wv * 4 + ks) * 64 + lane) * 8;
        f16x8 bh = *(const f16x8*)&s_w1h[off];
        f16x8 bl = *(const f16x8*)&s_w1l[off];
        aA = mmh(xh, bh, aA);
        aB = mmh(xh, bl, mmh(xl, bh, aB));
      }
#pragma unroll
      for (int reg = 0; reg < 4; ++reg) {
        int r = lg * 4 + reg, c = wv * 16 + l15;
        float act = lsw((aA[reg] + aB[reg] * LINV) + s_gb1[c]);
        u16 h, l; split2(act, h, l);
        AH1(0,r,c) = h; AH1(1,r,c) = l;
      }
    }
    __syncthreads();
    // L3 transposed (D' = W2^T h1^T): software-pipelined fp16 W2 stream
    float dw0v[4], dw1v[4];
#pragma unroll
    for (int reg = 0; reg < 4; ++reg) {
      dw0v[reg] = SDW((n - 1) & 1, l15, lg * 4 + reg);
      dw1v[reg] = SDW(n & 1,       l15, lg * 4 + reg);
    }
    f16x8 bfh[4], bfl[4];
#pragma unroll
    for (int ks = 0; ks < 4; ++ks) {
      bfh[ks] = *(const f16x8*)&AH1(0, l15, ks*32 + lg*8);
      bfl[ks] = *(const f16x8*)&AH1(1, l15, ks*32 + lg*8);
    }
#pragma unroll 1
    for (int j = 0; j < 8; j += 2) {
      const int ntA = wv * 8 + ((j + jrot) & 7);
      const int ntB = wv * 8 + ((j + 1 + jrot) & 7);
      L3_COMPUTE(whA, wlA, ntA);
      if (j < 6) L3_PREFETCH(whA, wlA, wv * 8 + ((j + 2 + jrot) & 7));
      L3_COMPUTE(whB, wlB, ntB);
      if (j < 6) L3_PREFETCH(whB, wlB, wv * 8 + ((j + 3 + jrot) & 7));
    }
    __syncthreads();
    // phase D: z_n = z + 0.5 w ; emit (ts, z.rw + rb)
#pragma unroll
    for (int i = 0; i < 2; ++i) {
      int r = wv * 2 + i, h = lane;
      float z = ZV(r,h);
      if (n > 0) { z += 0.5f * SW(r,h); ZV(r,h) = z; }
      float p = z * s_rw[h];
#pragma unroll
      for (int off = 32; off >= 1; off >>= 1) p += __shfl_xor(p, off);
      if (lane == 0) {
        int o = ((R + r) * T_STEPS + n) * 2;
        out[o] = tval; out[o + 1] = p + rbv;
      }
    }
  }
}

extern "C" void kernel_launch(void* const* d_in, const int* in_sizes, int n_in,
                              void* d_out, int out_size, void* d_ws, size_t ws_size,
                              hipStream_t stream) {
  (void)in_sizes; (void)n_in; (void)out_size; (void)ws_size;
  const float* ts = (const float*)d_in[0];
  const float* init_noise = (const float*)d_in[2];
  const float* dW  = (const float*)d_in[3];
  const float* iw0 = (const float*)d_in[4];
  const float* ib0 = (const float*)d_in[5];
  const float* iw1 = (const float*)d_in[6];
  const float* ib1 = (const float*)d_in[7];
  const float* iw2 = (const float*)d_in[8];
  const float* ib2 = (const float*)d_in[9];
  const float* gw0 = (const float*)d_in[10];
  const float* gb0 = (const float*)d_in[11];
  const float* gw1 = (const float*)d_in[12];
  const float* gb1 = (const float*)d_in[13];
  const float* gw2 = (const float*)d_in[14];
  const float* gb2 = (const float*)d_in[15];
  const float* rw  = (const float*)d_in[16];
  const float* rb  = (const float*)d_in[17];

  u16* ws = (u16*)d_ws;
  const int LO = 188416;  // elems per limb block
  u16* fiw0h = ws + 0;      u16* fiw0l = ws + LO + 0;
  u16* fiw1h = ws + 8192;   u16* fiw1l = ws + LO + 8192;
  u16* fiw2h = ws + 24576;  u16* fiw2l = ws + LO + 24576;
  u16* fgw0h = ws + 32768;  u16* fgw0l = ws + LO + 32768;
  u16* fgw1h = ws + 40960;  u16* fgw1l = ws + LO + 40960;
  u16* fgw2h = ws + 57344;  u16* fgw2l = ws + LO + 57344;

  frag_w2<<<32,  256, 0, stream>>>(iw0, 2, 128, 0, fiw0h, fiw0l, 8192);
  frag_w2<<<64,  256, 0, stream>>>(iw1, 4, 128, 0, fiw1h, fiw1l, 16384);
  frag_w2<<<32,  256, 0, stream>>>(iw2, 4, 64,  0, fiw2h, fiw2l, 8192);
  frag_w2<<<32,  256, 0, stream>>>(gw0, 2, 128, 1, fgw0h, fgw0l, 8192);
  frag_w2<<<64,  256, 0, stream>>>(gw1, 4, 128, 0, fgw1h, fgw1l, 16384);
  frag_w2<<<512, 256, 0, stream>>>(gw2, 4, 1024, 0, fgw2h, fgw2l, 131072);

  hipFuncSetAttribute((const void*)sde_gen,
                      hipFuncAttributeMaxDynamicSharedMemorySize, SMEM_BYTES);
  sde_gen<<<256, 512, SMEM_BYTES, stream>>>(
      ts, init_noise, dW, ib0, ib1, ib2, gw0, gb0, gb1, gb2, rw, rb,
      fiw0h, fiw0l, fiw1h, fiw1l, fiw2h, fiw2l,
      fgw0h, fgw0l, fgw1h, fgw1l, fgw2h, fgw2l,
      (float*)d_out);
}